// Round 8
// baseline (438.826 us; speedup 1.0000x reference)
//
#include <hip/hip_runtime.h>

typedef unsigned short u16;
typedef __attribute__((ext_vector_type(8))) short short8;
typedef __attribute__((ext_vector_type(4))) float f32x4;

#define DEV static __device__ __forceinline__

DEV float bf2f(u16 u) { return __uint_as_float(((unsigned)u) << 16); }
DEV u16 f2bf(float f) {
  unsigned u = __float_as_uint(f);
  return (u16)((u + 0x7fffu + ((u >> 16) & 1u)) >> 16);
}

// async global->LDS, 16B per lane; LDS dest = wave-uniform base + lane*16
DEV void cp16(void* lds, const void* g) {
  __builtin_amdgcn_global_load_lds(
      (const __attribute__((address_space(1))) unsigned int*)g,
      (__attribute__((address_space(3))) unsigned int*)lds, 16, 0, 0);
}

// dims: B=256, N=77, D=768, K=16, Dn=768, HID=512, L=2

// ---------------- cast fp32 -> bf16, 8 elems/thread ----------------
__global__ __launch_bounds__(256) void wcast_k(const float* __restrict__ src,
                                               u16* __restrict__ dst, int n8) {
  int i = blockIdx.x * 256 + threadIdx.x;
  if (i >= n8) return;
  f32x4 a = *(const f32x4*)&src[(size_t)i * 8];
  f32x4 b = *(const f32x4*)&src[(size_t)i * 8 + 4];
  short8 o;
#pragma unroll
  for (int e = 0; e < 4; ++e) { o[e] = (short)f2bf(a[e]); o[e + 4] = (short)f2bf(b[e]); }
  *(short8*)&dst[(size_t)i * 8] = o;
}

// ---------------- all weight transposes+casts in one launch ----------------
__global__ __launch_bounds__(256) void tcast_all(const float* __restrict__ Wk,
                                                 const float* __restrict__ Wv,
                                                 const float* __restrict__ We1,
                                                 const float* __restrict__ Wg,
                                                 u16* __restrict__ WkvT,
                                                 u16* __restrict__ We1T,
                                                 u16* __restrict__ WgT) {
  __shared__ float tile[32][33];
  const float* src; u16* dst; int C;
  switch (blockIdx.z) {
    case 0: src = Wk;           dst = WkvT;          C = 768; break;
    case 1: src = Wv;           dst = WkvT + 589824; C = 768; break;
    case 2: src = We1;          dst = We1T;          C = 512; break;
    case 3: src = We1 + 393216; dst = We1T + 393216; C = 512; break;
    case 4: src = Wg;           dst = WgT;           C = 768; break;
    default: src = Wg + 589824; dst = WgT + 589824;  C = 768; break;
  }
  int r0 = blockIdx.y * 32, c0 = blockIdx.x * 32;
  if (c0 >= C) return;
  int tr = threadIdx.x >> 5, tc = threadIdx.x & 31;
#pragma unroll
  for (int rr = 0; rr < 4; ++rr)
    tile[tr + rr * 8][tc] = src[(size_t)(r0 + tr + rr * 8) * C + c0 + tc];
  __syncthreads();
#pragma unroll
  for (int rr = 0; rr < 4; ++rr)
    dst[(size_t)(c0 + tr + rr * 8) * 768 + r0 + tc] = f2bf(tile[tc][tr + rr * 8]);
}

// ---------------- Q projection, split-K stage 1 ----------------
__global__ __launch_bounds__(256) void q_part(const float* __restrict__ nq,
                                              const float* __restrict__ Wq,
                                              float* __restrict__ Qpart) {
  int gid = blockIdx.x * 256 + threadIdx.x;  // 0..12287
  int s = blockIdx.y;
  int k = gid / 768, d = gid % 768;
  const float* nr = nq + k * 768 + s * 96;
  const float* wp = Wq + (size_t)(s * 96) * 768 + d;
  float s0 = 0.f, s1 = 0.f, s2 = 0.f, s3 = 0.f;
#pragma unroll
  for (int c = 0; c < 96; c += 4) {
    s0 += nr[c + 0] * wp[(size_t)(c + 0) * 768];
    s1 += nr[c + 1] * wp[(size_t)(c + 1) * 768];
    s2 += nr[c + 2] * wp[(size_t)(c + 2) * 768];
    s3 += nr[c + 3] * wp[(size_t)(c + 3) * 768];
  }
  Qpart[(size_t)s * 12288 + gid] = (s0 + s1) + (s2 + s3);
}

// ---------------- Q projection, stage 2: reduce + bias + cast ----------------
__global__ __launch_bounds__(256) void q_reduce(const float* __restrict__ Qpart,
                                                const float* __restrict__ bq,
                                                u16* __restrict__ Qb16) {
  int gid = blockIdx.x * 256 + threadIdx.x;  // 0..12287
  int d = gid % 768;
  float s = bq[d];
#pragma unroll
  for (int i = 0; i < 8; ++i) s += Qpart[(size_t)i * 12288 + gid];
  Qb16[gid] = f2bf(s);
}

// ---------------- big MFMA GEMM 128x128, async staging, swizzled LDS ----------------
__global__ __launch_bounds__(256) void gemm16(const u16* __restrict__ A,
                                              const u16* __restrict__ BT,
                                              const float* __restrict__ bias,
                                              u16* __restrict__ C, int N, int K,
                                              int mt, int nt) {
  __shared__ u16 As[128 * 32];
  __shared__ u16 Bs[128 * 32];
  int gid = blockIdx.x;
  int per = 8 * nt;
  int group = gid / per;
  int within = gid - group * per;
  int gsz = mt - group * 8; if (gsz > 8) gsz = 8;
  int mi = group * 8 + within % gsz;
  int ni = within / gsz;
  int m0 = mi * 128, n0 = ni * 128;
  int t = threadIdx.x;
  int wave = t >> 6, lane = t & 63, l16 = lane & 15, quad = lane >> 4;
  int wrow = (wave >> 1) * 64, wcol = (wave & 1) * 64;
  int r1 = wave * 32 + (lane >> 2);
  int r2 = r1 + 16;
  int cslot = lane & 3;
  int cg1 = (cslot ^ ((r1 >> 1) & 3)) * 8;
  int cg2 = (cslot ^ ((r2 >> 1) & 3)) * 8;

  f32x4 zero4 = {0.f, 0.f, 0.f, 0.f};
  f32x4 acc[4][4];
#pragma unroll
  for (int i = 0; i < 4; ++i)
#pragma unroll
    for (int j = 0; j < 4; ++j) acc[i][j] = zero4;

  for (int k0 = 0; k0 < K; k0 += 32) {
    cp16(&As[(wave * 32) * 32],      A + (size_t)(m0 + r1) * K + k0 + cg1);
    cp16(&As[(wave * 32 + 16) * 32], A + (size_t)(m0 + r2) * K + k0 + cg2);
    cp16(&Bs[(wave * 32) * 32],      BT + (size_t)(n0 + r1) * K + k0 + cg1);
    cp16(&Bs[(wave * 32 + 16) * 32], BT + (size_t)(n0 + r2) * K + k0 + cg2);
    __syncthreads();
    short8 fa[4], fb[4];
#pragma unroll
    for (int i = 0; i < 4; ++i) {
      int R = wrow + i * 16 + l16;
      fa[i] = *(const short8*)&As[R * 32 + (quad ^ ((R >> 1) & 3)) * 8];
    }
#pragma unroll
    for (int j = 0; j < 4; ++j) {
      int R = wcol + j * 16 + l16;
      fb[j] = *(const short8*)&Bs[R * 32 + (quad ^ ((R >> 1) & 3)) * 8];
    }
#pragma unroll
    for (int i = 0; i < 4; ++i)
#pragma unroll
      for (int j = 0; j < 4; ++j)
        acc[i][j] = __builtin_amdgcn_mfma_f32_16x16x32_bf16(fa[i], fb[j], acc[i][j], 0, 0, 0);
    __syncthreads();
  }

  // epilogue: row-contiguous store order for write coalescing
  int narr[4]; float bvj[4];
#pragma unroll
  for (int j = 0; j < 4; ++j) {
    narr[j] = n0 + wcol + j * 16 + l16;
    bvj[j] = bias ? bias[narr[j]] : 0.f;
  }
#pragma unroll
  for (int i = 0; i < 4; ++i)
#pragma unroll
    for (int r = 0; r < 4; ++r) {
      size_t mrow = (size_t)(m0 + wrow + i * 16 + quad * 4 + r) * N;
#pragma unroll
      for (int j = 0; j < 4; ++j)
        C[mrow + narr[j]] = f2bf(acc[i][j][r] + bvj[j]);
    }
}

// ---------------- scores via MFMA, register-direct Kt, fused softmax ----------------
__global__ __launch_bounds__(256) void score_mfma(const u16* __restrict__ Qb16,
                                                  const u16* __restrict__ Kt,
                                                  const int* __restrict__ mask,
                                                  float* __restrict__ Sout) {
  __shared__ u16 Qs[16 * 776];
  int t = threadIdx.x, wave = t >> 6, lane = t & 63, l16 = lane & 15, quad = lane >> 4;
  int m0 = blockIdx.x * 64;
#pragma unroll
  for (int r = 0; r < 6; ++r) {
    int idx = t + 256 * r;
    int row = idx / 96, c8 = idx % 96;
    *(short8*)&Qs[row * 776 + c8 * 8] = *(const short8*)&Qb16[row * 768 + c8 * 8];
  }
  __syncthreads();
  int row = m0 + wave * 16 + l16;
  const u16* kp = Kt + (size_t)row * 768 + quad * 8;
  f32x4 acc = {0.f, 0.f, 0.f, 0.f};
#pragma unroll
  for (int it = 0; it < 24; ++it) {
    short8 fa = *(const short8*)(kp + it * 32);
    short8 fb = *(const short8*)&Qs[l16 * 776 + it * 32 + quad * 8];
    acc = __builtin_amdgcn_mfma_f32_16x16x32_bf16(fa, fb, acc, 0, 0, 0);
  }
  const float scale = 0.1020620726159658f;  // (768/8)^-0.5
#pragma unroll
  for (int r = 0; r < 4; ++r) {
    int orow = m0 + wave * 16 + quad * 4 + r;
    float s = acc[r] * scale;
    if (mask[orow] == 0) s = -3.402823466e38f;  // finfo(f32).min
    float mx = s;
#pragma unroll
    for (int off = 1; off < 16; off <<= 1) mx = fmaxf(mx, __shfl_xor(mx, off));
    float e = __expf(s - mx);
    float sm = e;
#pragma unroll
    for (int off = 1; off < 16; off <<= 1) sm += __shfl_xor(sm, off);
    Sout[(size_t)orow * 16 + l16] = e / sm;
  }
}

// ---------------- PV: V = S^T @ Vt, gate blend. grid (256, 3) ----------------
__global__ __launch_bounds__(256) void pv_kernel(const float* __restrict__ Sg,
                                                 const u16* __restrict__ Vt,
                                                 const float* __restrict__ nq,
                                                 const float* __restrict__ gatep,
                                                 float* __restrict__ V32) {
  __shared__ float Ss[1232];
  int b = blockIdx.x, t = threadIdx.x;
  int d = blockIdx.y * 256 + t;
#pragma unroll
  for (int r = 0; r < 5; ++r) {
    int idx = t + 256 * r;
    if (idx < 1232) Ss[idx] = Sg[(size_t)b * 1232 + idx];
  }
  __syncthreads();
  float a[16];
#pragma unroll
  for (int k = 0; k < 16; ++k) a[k] = 0.f;
  const u16* vt = Vt + (size_t)b * 77 * 768;
  for (int n = 0; n < 77; ++n) {
    float g = bf2f(vt[(size_t)n * 768 + d]);
    const float* sr = &Ss[n * 16];
#pragma unroll
    for (int k = 0; k < 16; ++k) a[k] += sr[k] * g;
  }
  float gv = gatep[0];
  float gate = 1.f / (1.f + __expf(-gv));
  float og = 1.f - gate;
#pragma unroll
  for (int k = 0; k < 16; ++k)
    V32[(size_t)b * 12288 + (size_t)k * 768 + d] = og * a[k] + gate * nq[k * 768 + d];
}

// ---------------- fused GNN tail helpers ----------------
// per-batch 16xN GEMM: out(HG, bf16) = Vs(16x768 bf16 LDS) @ BT^T + bias.
// wave handles `tpw` consecutive 16-col tiles, processed in pairs.
DEV void batch_gemm(const u16* __restrict__ BT, const float* __restrict__ bias,
                    int tpw, const u16* Vs, u16* HG, int wave, int l16, int quad) {
  for (int p = 0; p < tpw; p += 2) {
    int c0 = (wave * tpw + p) * 16;
    int c1 = c0 + 16;
    const u16* wp0 = BT + (size_t)(c0 + l16) * 768 + quad * 8;
    const u16* wp1 = BT + (size_t)(c1 + l16) * 768 + quad * 8;
    f32x4 a0 = {0.f, 0.f, 0.f, 0.f}, a1 = {0.f, 0.f, 0.f, 0.f};
#pragma unroll
    for (int kk = 0; kk < 24; ++kk) {
      short8 fa = *(const short8*)&Vs[l16 * 776 + kk * 32 + quad * 8];
      short8 f0 = *(const short8*)(wp0 + kk * 32);
      short8 f1 = *(const short8*)(wp1 + kk * 32);
      a0 = __builtin_amdgcn_mfma_f32_16x16x32_bf16(fa, f0, a0, 0, 0, 0);
      a1 = __builtin_amdgcn_mfma_f32_16x16x32_bf16(fa, f1, a1, 0, 0, 0);
    }
    float b0 = bias ? bias[c0 + l16] : 0.f;
    float b1 = bias ? bias[c1 + l16] : 0.f;
#pragma unroll
    for (int r = 0; r < 4; ++r) {
      HG[(quad * 4 + r) * 1048 + c0 + l16] = f2bf(a0[r] + b0);
      HG[(quad * 4 + r) * 1048 + c1 + l16] = f2bf(a1[r] + b1);
    }
  }
}

// E[i][j] = sum_h relu(hi[i,h] + hj[j,h] + be1[h]) * We2[h]
DEV float edge_compute(const u16* HG, const float* be1s, const float* w2s,
                       int i, int j) {
  float e = 0.f;
  const u16* hi = &HG[i * 1048];
  const u16* hj = &HG[j * 1048 + 512];
#pragma unroll 2
  for (int h8 = 0; h8 < 64; ++h8) {
    short8 hv = *(const short8*)&hi[h8 * 8];
    short8 jv = *(const short8*)&hj[h8 * 8];
#pragma unroll
    for (int ee = 0; ee < 8; ++ee)
      e += fmaxf(bf2f((u16)hv[ee]) + bf2f((u16)jv[ee]) + be1s[h8 * 8 + ee], 0.f) *
           w2s[h8 * 8 + ee];
  }
  return e;
}

// ---------------- fused GNN tail: edge->A, 2x(G,combine), Vout, edge->E ----------------
// grid 256 (one block per batch), block 256.
__global__ __launch_bounds__(256) void tail_kernel(const float* __restrict__ V32g,
                                                   const u16* __restrict__ We1T,
                                                   const u16* __restrict__ WgT,
                                                   const float* __restrict__ bg,
                                                   const float* __restrict__ be1,
                                                   const float* __restrict__ We2,
                                                   const float* __restrict__ be2v,
                                                   float* __restrict__ Vout,
                                                   float* __restrict__ Eout) {
  __shared__ u16 Vs[16 * 776];    // V bf16 (24.8 KB)
  __shared__ u16 HG[16 * 1048];   // HIJ (1024 cols) or G (768 cols) (33.5 KB)
  __shared__ float As[256];       // adjacency softmax
  __shared__ float be1s[512];
  __shared__ float w2s[512];
  int b = blockIdx.x, t = threadIdx.x;
  int wave = t >> 6, lane = t & 63, l16 = lane & 15, quad = lane >> 4;
  int ii = t >> 4, jj = t & 15;

  // V -> registers (thread owns d = t + m*256 for all 16 nodes) + bf16 LDS mirror
  float vreg[16][3];
#pragma unroll
  for (int k = 0; k < 16; ++k)
#pragma unroll
    for (int m = 0; m < 3; ++m) {
      int d = t + m * 256;
      float v = V32g[(size_t)b * 12288 + (size_t)k * 768 + d];
      vreg[k][m] = v;
      Vs[k * 776 + d] = f2bf(v);
    }
  be1s[t] = be1[t]; be1s[t + 256] = be1[t + 256];
  w2s[t] = We2[t];  w2s[t + 256] = We2[t + 256];
  __syncthreads();

  // pre-GNN edge logits -> A (softmax over j)
  batch_gemm(We1T, nullptr, 16, Vs, HG, wave, l16, quad);
  __syncthreads();
  {
    float e = edge_compute(HG, be1s, w2s, ii, jj) + be2v[0];
    float mx = e;
#pragma unroll
    for (int off = 1; off < 16; off <<= 1) mx = fmaxf(mx, __shfl_xor(mx, off));
    float ex = __expf(e - mx);
    float sm = ex;
#pragma unroll
    for (int off = 1; off < 16; off <<= 1) sm += __shfl_xor(sm, off);
    As[t] = ex / sm;
  }
  __syncthreads();

  // two GNN layers: G = V@Wg_l + bg_l ; V += relu(A @ G)
  for (int l = 0; l < 2; ++l) {
    batch_gemm(WgT + l * 589824, bg + l * 768, 12, Vs, HG, wave, l16, quad);
    __syncthreads();
#pragma unroll
    for (int m = 0; m < 3; ++m) {
      int d = t + m * 256;
      float gv[16];
#pragma unroll
      for (int j2 = 0; j2 < 16; ++j2) gv[j2] = bf2f(HG[j2 * 1048 + d]);
#pragma unroll
      for (int i2 = 0; i2 < 16; ++i2) {
        float msg = 0.f;
#pragma unroll
        for (int j2 = 0; j2 < 16; ++j2) msg += As[i2 * 16 + j2] * gv[j2];
        vreg[i2][m] += fmaxf(msg, 0.f);
      }
    }
    __syncthreads();
#pragma unroll
    for (int k = 0; k < 16; ++k)
#pragma unroll
      for (int m = 0; m < 3; ++m)
        Vs[k * 776 + t + m * 256] = f2bf(vreg[k][m]);
    __syncthreads();
  }

  // final V out (fp32)
#pragma unroll
  for (int k = 0; k < 16; ++k)
#pragma unroll
    for (int m = 0; m < 3; ++m)
      Vout[(size_t)b * 12288 + (size_t)k * 768 + t + m * 256] = vreg[k][m];

  // post-GNN edge logits -> E
  batch_gemm(We1T, nullptr, 16, Vs, HG, wave, l16, quad);
  __syncthreads();
  Eout[(size_t)b * 256 + t] = edge_compute(HG, be1s, w2s, ii, jj) + be2v[0];
}

extern "C" void kernel_launch(void* const* d_in, const int* in_sizes, int n_in,
                              void* d_out, int out_size, void* d_ws, size_t ws_size,
                              hipStream_t stream) {
  const float* w    = (const float*)d_in[0];   // [256,77,768]
  const int*   mask = (const int*)d_in[1];     // [256,77]
  const float* nq   = (const float*)d_in[2];   // [1,16,768]
  const float* Wq   = (const float*)d_in[3];
  const float* bq   = (const float*)d_in[4];
  const float* Wk   = (const float*)d_in[5];
  const float* bk   = (const float*)d_in[6];
  const float* Wv   = (const float*)d_in[7];
  const float* bv   = (const float*)d_in[8];
  const float* We1  = (const float*)d_in[9];   // [1536,512]
  const float* be1  = (const float*)d_in[10];
  const float* We2  = (const float*)d_in[11];  // [512,1]
  const float* be2  = (const float*)d_in[12];
  const float* gate = (const float*)d_in[13];
  const float* Wg   = (const float*)d_in[14];  // [2,768,768]
  const float* bg   = (const float*)d_in[15];  // [2,768]

  // workspace (~86.4 MB)
  float* ws    = (float*)d_ws;
  float* V32   = ws;                    // 3,145,728 f
  float* Aws   = V32 + 3145728;         // 65,536 f (unused now)
  float* Qpart = Aws + 65536;           // 98,304 f
  u16* Qb16    = (u16*)(Qpart + 98304); // 12,288 u16
  u16* WkvT    = Qb16 + 12288;          // 1,179,648
  u16* We1T    = WkvT + 1179648;        // 786,432
  u16* WgT     = We1T + 786432;         // 1,179,648
  u16* V16     = WgT + 1179648;         // 3,145,728 (unused now)
  u16* w16     = V16 + 3145728;         // 15,138,816 (dead after V-gemm)
  u16* KVt     = w16 + 15138816;        // 15,138,816 (Kt then Vt; dead after pv)

  float* out  = (float*)d_out;
  float* Sout = out;                       // [256,77,16]
  float* Vout = out + 315392;              // [256,16,768]
  float* Eout = out + 315392 + 3145728;    // [256,16,16]

  dim3 blk(256);

  // prep: weights -> bf16 [n][k]; w -> bf16; Q -> bf16 (split-K)
  tcast_all<<<dim3(24, 24, 6), blk, 0, stream>>>(Wk, Wv, We1, Wg, WkvT, We1T, WgT);
  wcast_k<<<7392, blk, 0, stream>>>(w, w16, 1892352);
  q_part<<<dim3(48, 8), blk, 0, stream>>>(nq, Wq, Qpart);
  q_reduce<<<48, blk, 0, stream>>>(Qpart, bq, Qb16);

  // Kt = w16 @ WkT + bk ; scores+softmax -> Sout
  gemm16<<<924, blk, 0, stream>>>(w16, WkvT, bk, KVt, 768, 768, 154, 6);
  score_mfma<<<308, blk, 0, stream>>>(Qb16, KVt, mask, Sout);

  // Vt = w16 @ WvT + bv (same buffer) ; V = S^T Vt + gate blend
  gemm16<<<924, blk, 0, stream>>>(w16, WkvT + 589824, bv, KVt, 768, 768, 154, 6);
  pv_kernel<<<dim3(256, 3), blk, 0, stream>>>(Sout, KVt, nq, gate, V32);

  // fused GNN tail: edge->A, 2x(G-gemm + combine), Vout, edge->E
  tail_kernel<<<256, blk, 0, stream>>>(V32, We1T, WgT, bg, be1, We2, be2, Vout, Eout);
}

// Round 9
// 380.097 us; speedup vs baseline: 1.1545x; 1.1545x over previous
//
#include <hip/hip_runtime.h>

typedef unsigned short u16;
typedef __attribute__((ext_vector_type(8))) short short8;
typedef __attribute__((ext_vector_type(4))) float f32x4;

#define DEV static __device__ __forceinline__

DEV float bf2f(u16 u) { return __uint_as_float(((unsigned)u) << 16); }
DEV u16 f2bf(float f) {
  unsigned u = __float_as_uint(f);
  return (u16)((u + 0x7fffu + ((u >> 16) & 1u)) >> 16);
}

// async global->LDS, 16B per lane; LDS dest = wave-uniform base + lane*16
DEV void cp16(void* lds, const void* g) {
  __builtin_amdgcn_global_load_lds(
      (const __attribute__((address_space(1))) unsigned int*)g,
      (__attribute__((address_space(3))) unsigned int*)lds, 16, 0, 0);
}

// dims: B=256, N=77, D=768, K=16, Dn=768, HID=512, L=2

// ---------------- fused prep: weight transposes + w cast + Q split-K stage 1 ----------------
// grid 11232: [0,3456) tcast, [3456,10848) wcast, [10848,11232) q_part
__global__ __launch_bounds__(256) void prep_kernel(const float* __restrict__ w,
                                                   const float* __restrict__ nq,
                                                   const float* __restrict__ Wq,
                                                   const float* __restrict__ Wk,
                                                   const float* __restrict__ Wv,
                                                   const float* __restrict__ We1,
                                                   const float* __restrict__ Wg,
                                                   u16* __restrict__ w16,
                                                   u16* __restrict__ WkvT,
                                                   u16* __restrict__ We1T,
                                                   u16* __restrict__ WgT,
                                                   float* __restrict__ Qpart) {
  __shared__ float tile[32][33];
  int bi = blockIdx.x;
  if (bi < 3456) {
    // weight transpose+cast: src [768][C] fp32 -> dst [C][768] bf16
    int z = bi / 576, rem = bi % 576;
    int by = rem / 24, bx = rem % 24;
    const float* src; u16* dst; int C;
    switch (z) {
      case 0: src = Wk;           dst = WkvT;          C = 768; break;
      case 1: src = Wv;           dst = WkvT + 589824; C = 768; break;
      case 2: src = We1;          dst = We1T;          C = 512; break;
      case 3: src = We1 + 393216; dst = We1T + 393216; C = 512; break;
      case 4: src = Wg;           dst = WgT;           C = 768; break;
      default: src = Wg + 589824; dst = WgT + 589824;  C = 768; break;
    }
    int r0 = by * 32, c0 = bx * 32;
    if (c0 >= C) return;
    int tr = threadIdx.x >> 5, tc = threadIdx.x & 31;
#pragma unroll
    for (int rr = 0; rr < 4; ++rr)
      tile[tr + rr * 8][tc] = src[(size_t)(r0 + tr + rr * 8) * C + c0 + tc];
    __syncthreads();
#pragma unroll
    for (int rr = 0; rr < 4; ++rr)
      dst[(size_t)(c0 + tr + rr * 8) * 768 + r0 + tc] = f2bf(tile[tc][tr + rr * 8]);
  } else if (bi < 10848) {
    // w fp32 -> bf16, 8 elems/thread
    int i = (bi - 3456) * 256 + threadIdx.x;
    if (i >= 1892352) return;
    f32x4 a = *(const f32x4*)&w[(size_t)i * 8];
    f32x4 b = *(const f32x4*)&w[(size_t)i * 8 + 4];
    short8 o;
#pragma unroll
    for (int e = 0; e < 4; ++e) { o[e] = (short)f2bf(a[e]); o[e + 4] = (short)f2bf(b[e]); }
    *(short8*)&w16[(size_t)i * 8] = o;
  } else {
    // Q projection split-K partial: slice s, 96 k-elements
    int r = bi - 10848;               // 0..383
    int gid = (r % 48) * 256 + threadIdx.x;  // 0..12287
    int s = r / 48;                   // 0..7
    int k = gid / 768, d = gid % 768;
    const float* nr = nq + k * 768 + s * 96;
    const float* wp = Wq + (size_t)(s * 96) * 768 + d;
    float s0 = 0.f, s1 = 0.f, s2 = 0.f, s3 = 0.f;
#pragma unroll
    for (int c = 0; c < 96; c += 4) {
      s0 += nr[c + 0] * wp[(size_t)(c + 0) * 768];
      s1 += nr[c + 1] * wp[(size_t)(c + 1) * 768];
      s2 += nr[c + 2] * wp[(size_t)(c + 2) * 768];
      s3 += nr[c + 3] * wp[(size_t)(c + 3) * 768];
    }
    Qpart[(size_t)s * 12288 + gid] = (s0 + s1) + (s2 + s3);
  }
}

// ---------------- Q projection, stage 2: reduce + bias + cast ----------------
__global__ __launch_bounds__(256) void q_reduce(const float* __restrict__ Qpart,
                                                const float* __restrict__ bq,
                                                u16* __restrict__ Qb16) {
  int gid = blockIdx.x * 256 + threadIdx.x;  // 0..12287
  int d = gid % 768;
  float s = bq[d];
#pragma unroll
  for (int i = 0; i < 8; ++i) s += Qpart[(size_t)i * 12288 + gid];
  Qb16[gid] = f2bf(s);
}

// ---------------- big MFMA GEMM 128x128, async staging, swizzled LDS ----------------
__global__ __launch_bounds__(256) void gemm16(const u16* __restrict__ A,
                                              const u16* __restrict__ BT,
                                              const float* __restrict__ bias,
                                              u16* __restrict__ C, int N, int K,
                                              int mt, int nt) {
  __shared__ u16 As[128 * 32];
  __shared__ u16 Bs[128 * 32];
  int gid = blockIdx.x;
  int per = 8 * nt;
  int group = gid / per;
  int within = gid - group * per;
  int gsz = mt - group * 8; if (gsz > 8) gsz = 8;
  int mi = group * 8 + within % gsz;
  int ni = within / gsz;
  int m0 = mi * 128, n0 = ni * 128;
  int t = threadIdx.x;
  int wave = t >> 6, lane = t & 63, l16 = lane & 15, quad = lane >> 4;
  int wrow = (wave >> 1) * 64, wcol = (wave & 1) * 64;
  int r1 = wave * 32 + (lane >> 2);
  int r2 = r1 + 16;
  int cslot = lane & 3;
  int cg1 = (cslot ^ ((r1 >> 1) & 3)) * 8;
  int cg2 = (cslot ^ ((r2 >> 1) & 3)) * 8;

  f32x4 zero4 = {0.f, 0.f, 0.f, 0.f};
  f32x4 acc[4][4];
#pragma unroll
  for (int i = 0; i < 4; ++i)
#pragma unroll
    for (int j = 0; j < 4; ++j) acc[i][j] = zero4;

  for (int k0 = 0; k0 < K; k0 += 32) {
    cp16(&As[(wave * 32) * 32],      A + (size_t)(m0 + r1) * K + k0 + cg1);
    cp16(&As[(wave * 32 + 16) * 32], A + (size_t)(m0 + r2) * K + k0 + cg2);
    cp16(&Bs[(wave * 32) * 32],      BT + (size_t)(n0 + r1) * K + k0 + cg1);
    cp16(&Bs[(wave * 32 + 16) * 32], BT + (size_t)(n0 + r2) * K + k0 + cg2);
    __syncthreads();
    short8 fa[4], fb[4];
#pragma unroll
    for (int i = 0; i < 4; ++i) {
      int R = wrow + i * 16 + l16;
      fa[i] = *(const short8*)&As[R * 32 + (quad ^ ((R >> 1) & 3)) * 8];
    }
#pragma unroll
    for (int j = 0; j < 4; ++j) {
      int R = wcol + j * 16 + l16;
      fb[j] = *(const short8*)&Bs[R * 32 + (quad ^ ((R >> 1) & 3)) * 8];
    }
#pragma unroll
    for (int i = 0; i < 4; ++i)
#pragma unroll
      for (int j = 0; j < 4; ++j)
        acc[i][j] = __builtin_amdgcn_mfma_f32_16x16x32_bf16(fa[i], fb[j], acc[i][j], 0, 0, 0);
    __syncthreads();
  }

  // epilogue: row-contiguous store order for write coalescing
  int narr[4]; float bvj[4];
#pragma unroll
  for (int j = 0; j < 4; ++j) {
    narr[j] = n0 + wcol + j * 16 + l16;
    bvj[j] = bias ? bias[narr[j]] : 0.f;
  }
#pragma unroll
  for (int i = 0; i < 4; ++i)
#pragma unroll
    for (int r = 0; r < 4; ++r) {
      size_t mrow = (size_t)(m0 + wrow + i * 16 + quad * 4 + r) * N;
#pragma unroll
      for (int j = 0; j < 4; ++j)
        C[mrow + narr[j]] = f2bf(acc[i][j][r] + bvj[j]);
    }
}

// ---------------- small MFMA GEMM 64x128, dual-output fused launch ----------------
__global__ __launch_bounds__(256) void gemm16s(const u16* __restrict__ A,
                                               const u16* __restrict__ BT0,
                                               const float* __restrict__ bias0,
                                               u16* __restrict__ C0, int N0, int ntA,
                                               const u16* __restrict__ BT1,
                                               const float* __restrict__ bias1,
                                               u16* __restrict__ C1, int N1, int ntB,
                                               int K) {
  __shared__ u16 As[64 * 32];
  __shared__ u16 Bs[128 * 32];
  int nt = ntA + ntB;
  int mi = blockIdx.x / nt, ni = blockIdx.x % nt;
  const u16* BT; const float* bias; u16* C; int N, n0;
  if (ni < ntA) { BT = BT0; bias = bias0; C = C0; N = N0; n0 = ni * 128; }
  else          { BT = BT1; bias = bias1; C = C1; N = N1; n0 = (ni - ntA) * 128; }
  int m0 = mi * 64;
  int t = threadIdx.x;
  int wave = t >> 6, lane = t & 63, l16 = lane & 15, quad = lane >> 4;
  int ra = wave * 16 + (lane >> 2);
  int rb1 = wave * 32 + (lane >> 2);
  int rb2 = rb1 + 16;
  int cslot = lane & 3;
  int cga = (cslot ^ ((ra >> 1) & 3)) * 8;
  int cgb1 = (cslot ^ ((rb1 >> 1) & 3)) * 8;
  int cgb2 = (cslot ^ ((rb2 >> 1) & 3)) * 8;

  f32x4 zero4 = {0.f, 0.f, 0.f, 0.f};
  f32x4 acc[4][2];
#pragma unroll
  for (int i = 0; i < 4; ++i) { acc[i][0] = zero4; acc[i][1] = zero4; }

  for (int k0 = 0; k0 < K; k0 += 32) {
    cp16(&As[(wave * 16) * 32],      A + (size_t)(m0 + ra) * K + k0 + cga);
    cp16(&Bs[(wave * 32) * 32],      BT + (size_t)(n0 + rb1) * K + k0 + cgb1);
    cp16(&Bs[(wave * 32 + 16) * 32], BT + (size_t)(n0 + rb2) * K + k0 + cgb2);
    __syncthreads();
    short8 fa[4], fb[2];
#pragma unroll
    for (int i = 0; i < 4; ++i) {
      int R = i * 16 + l16;
      fa[i] = *(const short8*)&As[R * 32 + (quad ^ ((R >> 1) & 3)) * 8];
    }
#pragma unroll
    for (int j = 0; j < 2; ++j) {
      int R = wave * 32 + j * 16 + l16;
      fb[j] = *(const short8*)&Bs[R * 32 + (quad ^ ((R >> 1) & 3)) * 8];
    }
#pragma unroll
    for (int i = 0; i < 4; ++i)
#pragma unroll
      for (int j = 0; j < 2; ++j)
        acc[i][j] = __builtin_amdgcn_mfma_f32_16x16x32_bf16(fa[i], fb[j], acc[i][j], 0, 0, 0);
    __syncthreads();
  }

  int narr[2]; float bvj[2];
#pragma unroll
  for (int j = 0; j < 2; ++j) {
    narr[j] = n0 + wave * 32 + j * 16 + l16;
    bvj[j] = bias ? bias[narr[j]] : 0.f;
  }
#pragma unroll
  for (int i = 0; i < 4; ++i)
#pragma unroll
    for (int r = 0; r < 4; ++r) {
      size_t mrow = (size_t)(m0 + i * 16 + quad * 4 + r) * N;
#pragma unroll
      for (int j = 0; j < 2; ++j)
        C[mrow + narr[j]] = f2bf(acc[i][j][r] + bvj[j]);
    }
}

// ---------------- scores via MFMA, register-direct Kt, fused softmax ----------------
__global__ __launch_bounds__(256) void score_mfma(const u16* __restrict__ Qb16,
                                                  const u16* __restrict__ Kt,
                                                  const int* __restrict__ mask,
                                                  float* __restrict__ Sout) {
  __shared__ u16 Qs[16 * 776];
  int t = threadIdx.x, wave = t >> 6, lane = t & 63, l16 = lane & 15, quad = lane >> 4;
  int m0 = blockIdx.x * 64;
#pragma unroll
  for (int r = 0; r < 6; ++r) {
    int idx = t + 256 * r;
    int row = idx / 96, c8 = idx % 96;
    *(short8*)&Qs[row * 776 + c8 * 8] = *(const short8*)&Qb16[row * 768 + c8 * 8];
  }
  __syncthreads();
  int row = m0 + wave * 16 + l16;
  const u16* kp = Kt + (size_t)row * 768 + quad * 8;
  f32x4 acc = {0.f, 0.f, 0.f, 0.f};
#pragma unroll
  for (int it = 0; it < 24; ++it) {
    short8 fa = *(const short8*)(kp + it * 32);
    short8 fb = *(const short8*)&Qs[l16 * 776 + it * 32 + quad * 8];
    acc = __builtin_amdgcn_mfma_f32_16x16x32_bf16(fa, fb, acc, 0, 0, 0);
  }
  const float scale = 0.1020620726159658f;  // (768/8)^-0.5
#pragma unroll
  for (int r = 0; r < 4; ++r) {
    int orow = m0 + wave * 16 + quad * 4 + r;
    float s = acc[r] * scale;
    if (mask[orow] == 0) s = -3.402823466e38f;  // finfo(f32).min
    float mx = s;
#pragma unroll
    for (int off = 1; off < 16; off <<= 1) mx = fmaxf(mx, __shfl_xor(mx, off));
    float e = __expf(s - mx);
    float sm = e;
#pragma unroll
    for (int off = 1; off < 16; off <<= 1) sm += __shfl_xor(sm, off);
    Sout[(size_t)orow * 16 + l16] = e / sm;
  }
}

// ---------------- PV: V = S^T @ Vt, gate blend. grid (256, 3) ----------------
__global__ __launch_bounds__(256) void pv_kernel(const float* __restrict__ Sg,
                                                 const u16* __restrict__ Vt,
                                                 const float* __restrict__ nq,
                                                 const float* __restrict__ gatep,
                                                 float* __restrict__ V32,
                                                 u16* __restrict__ V16) {
  __shared__ float Ss[1232];
  int b = blockIdx.x, t = threadIdx.x;
  int d = blockIdx.y * 256 + t;
#pragma unroll
  for (int r = 0; r < 5; ++r) {
    int idx = t + 256 * r;
    if (idx < 1232) Ss[idx] = Sg[(size_t)b * 1232 + idx];
  }
  __syncthreads();
  float a[16];
#pragma unroll
  for (int k = 0; k < 16; ++k) a[k] = 0.f;
  const u16* vt = Vt + (size_t)b * 77 * 768;
  for (int n = 0; n < 77; ++n) {
    float g = bf2f(vt[(size_t)n * 768 + d]);
    const float* sr = &Ss[n * 16];
#pragma unroll
    for (int k = 0; k < 16; ++k) a[k] += sr[k] * g;
  }
  float gv = gatep[0];
  float gate = 1.f / (1.f + __expf(-gv));
  float og = 1.f - gate;
#pragma unroll
  for (int k = 0; k < 16; ++k) {
    float val = og * a[k] + gate * nq[k * 768 + d];
    size_t idx = (size_t)b * 12288 + (size_t)k * 768 + d;
    V32[idx] = val;
    V16[idx] = f2bf(val);
  }
}

// ---------------- fused edge(A) + combine(layer0): per batch ----------------
// HIJ bf16 [4096][1024], G bf16 [4096][768]. Computes A = softmax(E), then
// V += relu(A @ G), updating V32 and V16.
__global__ __launch_bounds__(256) void edgecombine_kernel(const u16* __restrict__ HIJ,
                                                          const u16* __restrict__ G,
                                                          const float* __restrict__ be1,
                                                          const float* __restrict__ We2,
                                                          const float* __restrict__ be2v,
                                                          float* __restrict__ Aws,
                                                          float* __restrict__ V32,
                                                          u16* __restrict__ V16) {
  __shared__ float As[256];
  __shared__ float buf[16 * 772];  // overlaid: edge phase then Gs
  float* hiS = buf;                // 16*260
  float* hjS = buf + 4160;         // 16*260
  float* be1s = buf + 8320;        // 512
  float* w2s  = buf + 8832;        // 512
  int b = blockIdx.x, t = threadIdx.x;
  be1s[t] = be1[t]; be1s[t + 256] = be1[t + 256];
  w2s[t] = We2[t];  w2s[t + 256] = We2[t + 256];

  int i = t >> 4, jj = t & 15;
  float e = 0.f;
  for (int half = 0; half < 2; ++half) {
    __syncthreads();
#pragma unroll
    for (int r = 0; r < 2; ++r) {
      int idx = t + 256 * r;          // 512 short8 chunks per half
      int row = idx >> 5, c8 = idx & 31;
      const u16* src = &HIJ[(size_t)(b * 16 + row) * 1024 + half * 256 + c8 * 8];
      short8 hv = *(const short8*)src;
      short8 jv = *(const short8*)(src + 512);
      f32x4 l0, l1, m0v, m1v;
#pragma unroll
      for (int ee = 0; ee < 4; ++ee) {
        l0[ee] = bf2f((u16)hv[ee]); l1[ee] = bf2f((u16)hv[ee + 4]);
        m0v[ee] = bf2f((u16)jv[ee]); m1v[ee] = bf2f((u16)jv[ee + 4]);
      }
      *(f32x4*)&hiS[row * 260 + c8 * 8] = l0;
      *(f32x4*)&hiS[row * 260 + c8 * 8 + 4] = l1;
      *(f32x4*)&hjS[row * 260 + c8 * 8] = m0v;
      *(f32x4*)&hjS[row * 260 + c8 * 8 + 4] = m1v;
    }
    __syncthreads();
    const float* hi = &hiS[i * 260];
    const float* hj = &hjS[jj * 260];
    const float* b1 = &be1s[half * 256];
    const float* w2 = &w2s[half * 256];
#pragma unroll 2
    for (int h4 = 0; h4 < 64; ++h4) {
      f32x4 hv = *(const f32x4*)&hi[h4 * 4];
      f32x4 jv = *(const f32x4*)&hj[h4 * 4];
      f32x4 bv = *(const f32x4*)&b1[h4 * 4];
      f32x4 wv = *(const f32x4*)&w2[h4 * 4];
#pragma unroll
      for (int ee = 0; ee < 4; ++ee)
        e += fmaxf(hv[ee] + jv[ee] + bv[ee], 0.f) * wv[ee];
    }
  }
  e += be2v[0];

  {
    float mx = e;
#pragma unroll
    for (int off = 1; off < 16; off <<= 1) mx = fmaxf(mx, __shfl_xor(mx, off));
    float ex = __expf(e - mx);
    float sm = ex;
#pragma unroll
    for (int off = 1; off < 16; off <<= 1) sm += __shfl_xor(sm, off);
    As[t] = ex / sm;
    Aws[(size_t)b * 256 + t] = As[t];
  }
  __syncthreads();

  // combine phase: Gs overlays buf (edge data dead)
  float* Gs = buf;  // 16*772
#pragma unroll
  for (int r = 0; r < 6; ++r) {
    int idx = t + 256 * r;
    int row = idx / 96, c8 = idx % 96;
    short8 gv8 = *(const short8*)&G[(size_t)(b * 16 + row) * 768 + c8 * 8];
    f32x4 l0, l1;
#pragma unroll
    for (int ee = 0; ee < 4; ++ee) { l0[ee] = bf2f((u16)gv8[ee]); l1[ee] = bf2f((u16)gv8[ee + 4]); }
    *(f32x4*)&Gs[row * 772 + c8 * 8] = l0;
    *(f32x4*)&Gs[row * 772 + c8 * 8 + 4] = l1;
  }
  __syncthreads();
#pragma unroll
  for (int m = 0; m < 3; ++m) {
    int d = t + m * 256;
    float gv[16];
#pragma unroll
    for (int j2 = 0; j2 < 16; ++j2) gv[j2] = Gs[j2 * 772 + d];
#pragma unroll
    for (int i2 = 0; i2 < 16; ++i2) {
      float msg = 0.f;
#pragma unroll
      for (int j2 = 0; j2 < 16; ++j2) msg += As[i2 * 16 + j2] * gv[j2];
      size_t idx = (size_t)b * 12288 + (size_t)i2 * 768 + d;
      float v = V32[idx] + fmaxf(msg, 0.f);
      V32[idx] = v;
      V16[idx] = f2bf(v);
    }
  }
}

// ---------------- edge logits (E output) per batch; HIJ bf16 ----------------
__global__ __launch_bounds__(256) void edge_kernel(const u16* __restrict__ HIJ,
                                                   const float* __restrict__ be1,
                                                   const float* __restrict__ We2,
                                                   const float* __restrict__ be2v,
                                                   float* __restrict__ Eout) {
  __shared__ float hiS[16 * 260];
  __shared__ float hjS[16 * 260];
  __shared__ float be1s[512];
  __shared__ float w2s[512];
  int b = blockIdx.x, t = threadIdx.x;
  be1s[t] = be1[t]; be1s[t + 256] = be1[t + 256];
  w2s[t] = We2[t];  w2s[t + 256] = We2[t + 256];

  int i = t >> 4, jj = t & 15;
  float e = 0.f;
  for (int half = 0; half < 2; ++half) {
    __syncthreads();
#pragma unroll
    for (int r = 0; r < 2; ++r) {
      int idx = t + 256 * r;
      int row = idx >> 5, c8 = idx & 31;
      const u16* src = &HIJ[(size_t)(b * 16 + row) * 1024 + half * 256 + c8 * 8];
      short8 hv = *(const short8*)src;
      short8 jv = *(const short8*)(src + 512);
      f32x4 l0, l1, m0v, m1v;
#pragma unroll
      for (int ee = 0; ee < 4; ++ee) {
        l0[ee] = bf2f((u16)hv[ee]); l1[ee] = bf2f((u16)hv[ee + 4]);
        m0v[ee] = bf2f((u16)jv[ee]); m1v[ee] = bf2f((u16)jv[ee + 4]);
      }
      *(f32x4*)&hiS[row * 260 + c8 * 8] = l0;
      *(f32x4*)&hiS[row * 260 + c8 * 8 + 4] = l1;
      *(f32x4*)&hjS[row * 260 + c8 * 8] = m0v;
      *(f32x4*)&hjS[row * 260 + c8 * 8 + 4] = m1v;
    }
    __syncthreads();
    const float* hi = &hiS[i * 260];
    const float* hj = &hjS[jj * 260];
    const float* b1 = &be1s[half * 256];
    const float* w2 = &w2s[half * 256];
#pragma unroll 2
    for (int h4 = 0; h4 < 64; ++h4) {
      f32x4 hv = *(const f32x4*)&hi[h4 * 4];
      f32x4 jv = *(const f32x4*)&hj[h4 * 4];
      f32x4 bv = *(const f32x4*)&b1[h4 * 4];
      f32x4 wv = *(const f32x4*)&w2[h4 * 4];
#pragma unroll
      for (int ee = 0; ee < 4; ++ee)
        e += fmaxf(hv[ee] + jv[ee] + bv[ee], 0.f) * wv[ee];
    }
  }
  Eout[(size_t)b * 256 + t] = e + be2v[0];
}

// ---------------- GNN combine: V += relu(A @ G); G bf16 ----------------
__global__ __launch_bounds__(256) void combine_kernel(const float* __restrict__ Aws,
                                                      const u16* __restrict__ G,
                                                      float* __restrict__ V32,
                                                      u16* __restrict__ V16,
                                                      float* __restrict__ Vout) {
  __shared__ float Gs[16 * 772];
  __shared__ float As[256];
  int b = blockIdx.x, t = threadIdx.x;
#pragma unroll
  for (int r = 0; r < 6; ++r) {
    int idx = t + 256 * r;
    int row = idx / 96, c8 = idx % 96;
    short8 gv8 = *(const short8*)&G[(size_t)(b * 16 + row) * 768 + c8 * 8];
    f32x4 l0, l1;
#pragma unroll
    for (int ee = 0; ee < 4; ++ee) { l0[ee] = bf2f((u16)gv8[ee]); l1[ee] = bf2f((u16)gv8[ee + 4]); }
    *(f32x4*)&Gs[row * 772 + c8 * 8] = l0;
    *(f32x4*)&Gs[row * 772 + c8 * 8 + 4] = l1;
  }
  As[t] = Aws[(size_t)b * 256 + t];
  __syncthreads();
#pragma unroll
  for (int m = 0; m < 3; ++m) {
    int d = t + m * 256;
    float gv[16];
#pragma unroll
    for (int j = 0; j < 16; ++j) gv[j] = Gs[j * 772 + d];
#pragma unroll
    for (int i = 0; i < 16; ++i) {
      float msg = 0.f;
#pragma unroll
      for (int j = 0; j < 16; ++j) msg += As[i * 16 + j] * gv[j];
      size_t idx = (size_t)b * 12288 + (size_t)i * 768 + d;
      float v = V32[idx] + fmaxf(msg, 0.f);
      V32[idx] = v;
      V16[idx] = f2bf(v);
      if (Vout) Vout[idx] = v;
    }
  }
}

extern "C" void kernel_launch(void* const* d_in, const int* in_sizes, int n_in,
                              void* d_out, int out_size, void* d_ws, size_t ws_size,
                              hipStream_t stream) {
  const float* w    = (const float*)d_in[0];   // [256,77,768]
  const int*   mask = (const int*)d_in[1];     // [256,77]
  const float* nq   = (const float*)d_in[2];   // [1,16,768]
  const float* Wq   = (const float*)d_in[3];
  const float* bq   = (const float*)d_in[4];
  const float* Wk   = (const float*)d_in[5];
  const float* bk   = (const float*)d_in[6];
  const float* Wv   = (const float*)d_in[7];
  const float* bv   = (const float*)d_in[8];
  const float* We1  = (const float*)d_in[9];   // [1536,512]
  const float* be1  = (const float*)d_in[10];
  const float* We2  = (const float*)d_in[11];  // [512,1]
  const float* be2  = (const float*)d_in[12];
  const float* gate = (const float*)d_in[13];
  const float* Wg   = (const float*)d_in[14];  // [2,768,768]
  const float* bg   = (const float*)d_in[15];  // [2,768]

  // workspace (~86.4 MB)
  float* ws    = (float*)d_ws;
  float* V32   = ws;                    // 3,145,728 f
  float* Aws   = V32 + 3145728;         // 65,536 f
  float* Qpart = Aws + 65536;           // 98,304 f
  u16* Qb16    = (u16*)(Qpart + 98304); // 12,288 u16
  u16* WkvT    = Qb16 + 12288;          // 1,179,648
  u16* We1T    = WkvT + 1179648;        // 786,432
  u16* WgT     = We1T + 786432;         // 1,179,648
  u16* V16     = WgT + 1179648;         // 3,145,728
  u16* w16     = V16 + 3145728;         // 15,138,816 (dead after V-gemm)
  u16* KVt     = w16 + 15138816;        // 15,138,816 (Kt then Vt; dead after pv)
  // unions into dead w16 region (after pv):
  u16* HIJ     = w16;                   // 4,194,304 u16
  u16* Gws     = w16 + 4194304;         // 3,145,728 u16

  float* out  = (float*)d_out;
  float* Sout = out;                       // [256,77,16]
  float* Vout = out + 315392;              // [256,16,768]
  float* Eout = out + 315392 + 3145728;    // [256,16,16]

  dim3 blk(256);

  // fused prep: weights -> bf16 [n][k]; w -> bf16; Q split-K partials
  prep_kernel<<<11232, blk, 0, stream>>>(w, nq, Wq, Wk, Wv, We1, Wg,
                                         w16, WkvT, We1T, WgT, Qpart);
  q_reduce<<<48, blk, 0, stream>>>(Qpart, bq, Qb16);

  // Kt = w16 @ WkT + bk ; scores+softmax -> Sout
  gemm16<<<924, blk, 0, stream>>>(w16, WkvT, bk, KVt, 768, 768, 154, 6);
  score_mfma<<<308, blk, 0, stream>>>(Qb16, KVt, mask, Sout);

  // Vt = w16 @ WvT + bv (same buffer) ; V = S^T Vt + gate blend
  gemm16<<<924, blk, 0, stream>>>(w16, WkvT + 589824, bv, KVt, 768, 768, 154, 6);
  pv_kernel<<<dim3(256, 3), blk, 0, stream>>>(Sout, KVt, nq, gate, V32, V16);

  // fused: pre-GNN edge gemm (HIJ, 8 n-tiles) + GNN layer-0 gemm (Gws, 6 n-tiles)
  gemm16s<<<896, blk, 0, stream>>>(V16, We1T, nullptr, HIJ, 1024, 8,
                                   WgT, bg, Gws, 768, 6, 768);
  // fused: edge logits -> A + combine layer 0
  edgecombine_kernel<<<256, blk, 0, stream>>>(HIJ, Gws, be1, We2, be2, Aws, V32, V16);

  // GNN layer 1
  gemm16s<<<384, blk, 0, stream>>>(V16, WgT + 589824, bg + 768, Gws, 768, 6,
                                   WgT + 589824, bg + 768, Gws, 768, 0, 768);
  combine_kernel<<<256, blk, 0, stream>>>(Aws, Gws, V32, V16, Vout);

  // post-GNN edge logits -> E
  gemm16s<<<512, blk, 0, stream>>>(V16, We1T, nullptr, HIJ, 1024, 8,
                                   We1T, nullptr, HIJ, 1024, 0, 768);
  edge_kernel<<<256, blk, 0, stream>>>(HIJ, be1, We2, be2, Eout);
}